// Round 7
// baseline (992.099 us; speedup 1.0000x reference)
//
#include <hip/hip_runtime.h>
#include <hip/hip_bf16.h>
#include <math.h>

// QuantumNeuralLayer collapsed: fused = x @ Weq^T + beq, Weq = Wf @ W16r.
// R7 GEMM: hybrid operand paths. A: direct global->register fragment loads
// (L1 serves the 4-wave duplication). B: LDS ring-4 (16 KB slots, 64 KiB),
// 2-bit XOR bank swizzle (slot^=(row&3), both-sides), zero excess conflicts.
// Per 32-K chunk: {stage B(c+3); ds_read B(c+1); 32 MFMA; load A(c+2);
// vmcnt(10); barrier}. Counted vmcnt never 0 mid-loop.

typedef __bf16 bf16_t;
typedef __bf16 bf16x8 __attribute__((ext_vector_type(8)));
typedef __bf16 bf16x4 __attribute__((ext_vector_type(4)));
typedef float  f32x4  __attribute__((ext_vector_type(4)));

#define KC 32768
#define OD 2048
#define ID 2048
#define BSROWS 8192

#define GLL16(g, l) __builtin_amdgcn_global_load_lds( \
    (const __attribute__((address_space(1))) void*)(g), \
    (__attribute__((address_space(3))) void*)(l), 16, 0, 0)

__device__ __forceinline__ float wave_sum(float v) {
#pragma unroll
  for (int o = 32; o > 0; o >>= 1) v += __shfl_down(v, o, 64);
  return v;
}

// ---------------------------------------------------------------------------
// C[m][n] (f32) = A[m][k] * B[n][k]^T, bf16 in. 512 thr = 8 waves (2M x 4N),
// per-wave output 128x64. B-chunk slot = 256 rows x 32 k = 16 KB, ring-4.
// ---------------------------------------------------------------------------
__global__ __launch_bounds__(512, 2) void gemm256(
    const bf16_t* __restrict__ A, const bf16_t* __restrict__ B,
    float* __restrict__ C, int M, int N, int lda, int ldb,
    int Ks, int nbn, int mn)
{
  __shared__ char lds[65536];   // B ring-4: slot s at s*16384
  const int tid  = threadIdx.x;
  const int lane = tid & 63;
  const int wave = tid >> 6;

  // T1: bijective XCD swizzle (gridDim.x % 8 == 0)
  const int nwg = gridDim.x;
  const int per = nwg >> 3;
  const int swz = (blockIdx.x & 7) * per + (blockIdx.x >> 3);
  const int z   = swz / mn;
  const int rem = swz - z * mn;
  const int bm  = (rem / nbn) * 256;
  const int bn  = (rem % nbn) * 256;
  const int k0  = z * Ks;
  float* Cz = C + (size_t)z * ((size_t)M * (size_t)N);

  const int wr = wave >> 2, wc = wave & 3;
  const int wrbase = wr * 128, wcbase = wc * 64;

  // A direct: lane reads A[bm+wrbase+m*16+(lane&15)][k0 + c*32 + (lane>>4)*8]
  const bf16_t* gAr = A + (size_t)(bm + wrbase + (lane & 15)) * lda
                        + k0 + ((lane >> 4) * 8);

  // B stage: thread -> row tid>>2 (and +128); 16B slot inverse-swizzled (^row&3)
  const int srow = tid >> 2;
  const int scol = ((tid & 3) ^ ((tid >> 2) & 3)) * 8;
  const bf16_t* gBs = B + (size_t)(bn + srow) * ldb + k0 + scol;
  const int ldst = wave * 1024;  // + lane*16 implied

  // B read: row = wcbase + n*16 + (lane&15); slot = (lane>>4) ^ (row&3)
  const int boff = (wcbase + (lane & 15)) * 64 + (((lane >> 4) ^ (lane & 3)) * 16);

  f32x4 acc[8][4] = {};
  bf16x8 aA[8], aB[8], bgA[4], bgB[4];
  const int NC = Ks >> 5;   // K=32 chunks (256 / 64); even, >= 8

#define STAGEB(c) do {                                            \
    char* d_ = lds + (((c) & 3) << 14);                           \
    const bf16_t* s_ = gBs + (size_t)(c) * 32;                    \
    GLL16(s_,                     d_ + ldst);                     \
    GLL16(s_ + (size_t)128 * ldb, d_ + 8192 + ldst);              \
  } while (0)

#define LOADA(c, ar) do {                                         \
    const bf16_t* p_ = gAr + (size_t)(c) * 32;                    \
    _Pragma("unroll")                                             \
    for (int m = 0; m < 8; ++m)                                   \
      ar[m] = *reinterpret_cast<const bf16x8*>(p_ + (size_t)(m * 16) * lda); \
  } while (0)

#define READB(c, bg) do {                                         \
    const char* p_ = lds + (((c) & 3) << 14) + boff;              \
    _Pragma("unroll")                                             \
    for (int n = 0; n < 4; ++n)                                   \
      bg[n] = *reinterpret_cast<const bf16x8*>(p_ + n * 1024);    \
  } while (0)

#define MFMA32(af, bg) do {                                       \
    __builtin_amdgcn_s_setprio(1);                                \
    _Pragma("unroll")                                             \
    for (int m = 0; m < 8; ++m)                                   \
      _Pragma("unroll")                                           \
      for (int n = 0; n < 4; ++n)                                 \
        acc[m][n] = __builtin_amdgcn_mfma_f32_16x16x32_bf16(      \
            af[m], bg[n], acc[m][n], 0, 0, 0);                    \
    __builtin_amdgcn_s_setprio(0);                                \
  } while (0)

  // chunk c: MFMA on (aC,bgC); read B(c+1)->bgN; stage B(c+3); load A(c+2)->aC
#define CHUNK(c, aC, aN, bgC, bgN) do {                           \
    if ((c) + 3 < NC) STAGEB((c) + 3);                            \
    if ((c) + 1 < NC) READB((c) + 1, bgN);                        \
    MFMA32(aC, bgC);                                              \
    if ((c) + 2 < NC) LOADA((c) + 2, aC);                         \
    if ((c) + 4 <= NC)      asm volatile("s_waitcnt vmcnt(10)" ::: "memory"); \
    else if ((c) + 3 == NC) asm volatile("s_waitcnt vmcnt(8)"  ::: "memory"); \
    else if ((c) + 2 == NC) asm volatile("s_waitcnt vmcnt(0)"  ::: "memory"); \
    __builtin_amdgcn_s_barrier();                                 \
  } while (0)

  // prologue (order pinned so the vmcnt(10) drain set = {B0,B1,A0}):
  STAGEB(0); STAGEB(1);
  asm volatile("" ::: "memory");
  LOADA(0, aA);
  asm volatile("" ::: "memory");
  STAGEB(2); LOADA(1, aB);
  asm volatile("s_waitcnt vmcnt(10)" ::: "memory");
  __builtin_amdgcn_s_barrier();
  READB(0, bgA);

#pragma unroll 1
  for (int c = 0; c < NC; c += 2) {
    CHUNK(c,     aA, aB, bgA, bgB);
    CHUNK(c + 1, aB, aA, bgB, bgA);
  }
#undef CHUNK
#undef MFMA32
#undef READB
#undef LOADA
#undef STAGEB

  // C/D layout (m89-verified): col = lane&15, row = (lane>>4)*4 + j
  const int cr = (lane >> 4) * 4, cc = lane & 15;
#pragma unroll
  for (int m = 0; m < 8; ++m)
#pragma unroll
    for (int n = 0; n < 4; ++n) {
      size_t base = (size_t)(bm + wrbase + m * 16 + cr) * N + (bn + wcbase + n * 16 + cc);
#pragma unroll
      for (int j = 0; j < 4; ++j)
        Cz[base + (size_t)j * N] = acc[m][n][j];
    }
}

// ---------------- Wf f32 -> bf16, and beq partial = sum_c b16[c]*Wf[o,c] ----------
__global__ void conv_wf_beq(const float* __restrict__ Wf, const float* __restrict__ b16,
                            bf16_t* __restrict__ Wf16, float* __restrict__ beq)
{
  const int o  = blockIdx.y;
  const int cb = blockIdx.x * 2048;
  const int t  = threadIdx.x;
  const size_t gbase = (size_t)o * KC + cb + t * 8;
  const float4 v0 = *(const float4*)(Wf + gbase);
  const float4 v1 = *(const float4*)(Wf + gbase + 4);
  const float4 b0 = *(const float4*)(b16 + cb + t * 8);
  const float4 b1 = *(const float4*)(b16 + cb + t * 8 + 4);
  bf16x8 r;
  r[0] = (bf16_t)v0.x; r[1] = (bf16_t)v0.y; r[2] = (bf16_t)v0.z; r[3] = (bf16_t)v0.w;
  r[4] = (bf16_t)v1.x; r[5] = (bf16_t)v1.y; r[6] = (bf16_t)v1.z; r[7] = (bf16_t)v1.w;
  *reinterpret_cast<bf16x8*>(Wf16 + gbase) = r;
  float s = v0.x * b0.x + v0.y * b0.y + v0.z * b0.z + v0.w * b0.w
          + v1.x * b1.x + v1.y * b1.y + v1.z * b1.z + v1.w * b1.w;
  s = wave_sum(s);
  __shared__ float red[4];
  if ((t & 63) == 0) red[t >> 6] = s;
  __syncthreads();
  if (t == 0) atomicAdd(beq + o, red[0] + red[1] + red[2] + red[3]);
}

// ---------------- W16 [c][i] f32 -> W16T [i][c] bf16 (vectorized writes) ----------
__global__ void transpose_w16(const float* __restrict__ W, bf16_t* __restrict__ T)
{
  __shared__ bf16_t tile[64][65];
  const int cb = blockIdx.x * 64;
  const int ib = blockIdx.y * 64;
  const int tx = threadIdx.x & 63;
  const int ty = threadIdx.x >> 6;
#pragma unroll
  for (int r = ty; r < 64; r += 4)
    tile[r][tx] = (bf16_t)W[(size_t)(cb + r) * ID + ib + tx];
  __syncthreads();
  const int orow = threadIdx.x >> 3;
  const int oc8  = (threadIdx.x & 7) * 8;
#pragma unroll
  for (int rr = 0; rr < 2; ++rr) {
    const int r = orow + rr * 32;
    bf16x8 v;
#pragma unroll
    for (int j = 0; j < 8; ++j) v[j] = tile[oc8 + j][r];
    *reinterpret_cast<bf16x8*>(T + (size_t)(ib + r) * KC + cb + oc8) = v;
  }
}

// ---------------- x f32 -> bf16 ---------------------------------------------------
__global__ void conv_x(const float* __restrict__ X, bf16_t* __restrict__ X16)
{
  const size_t i = ((size_t)blockIdx.x * 256 + threadIdx.x) * 8;
  const float4 v0 = *(const float4*)(X + i);
  const float4 v1 = *(const float4*)(X + i + 4);
  bf16x8 r;
  r[0] = (bf16_t)v0.x; r[1] = (bf16_t)v0.y; r[2] = (bf16_t)v0.z; r[3] = (bf16_t)v0.w;
  r[4] = (bf16_t)v1.x; r[5] = (bf16_t)v1.y; r[6] = (bf16_t)v1.z; r[7] = (bf16_t)v1.w;
  *reinterpret_cast<bf16x8*>(X16 + i) = r;
}

// ---------------- reduce 4 K-split slabs -> Weq bf16 ------------------------------
__global__ void reduce_weq(const float* __restrict__ slabs, bf16_t* __restrict__ Weq)
{
  const size_t MN = (size_t)OD * ID;
  const size_t i = ((size_t)blockIdx.x * 256 + threadIdx.x) * 4;
  float4 a = *(const float4*)(slabs + i);
  float4 b = *(const float4*)(slabs + MN + i);
  float4 c = *(const float4*)(slabs + 2 * MN + i);
  float4 d = *(const float4*)(slabs + 3 * MN + i);
  bf16x4 r;
  r[0] = (bf16_t)(a.x + b.x + c.x + d.x);
  r[1] = (bf16_t)(a.y + b.y + c.y + d.y);
  r[2] = (bf16_t)(a.z + b.z + c.z + d.z);
  r[3] = (bf16_t)(a.w + b.w + c.w + d.w);
  *reinterpret_cast<bf16x4*>(Weq + i) = r;
}

// ---------------- bias + LayerNorm + exact GELU -----------------------------------
__global__ __launch_bounds__(256) void ln_gelu(
    const float* __restrict__ fused, const float* __restrict__ beq,
    const float* __restrict__ bfv, const float* __restrict__ gamma,
    const float* __restrict__ beta, float* __restrict__ out)
{
  const int row = blockIdx.x;
  const int t = threadIdx.x;
  const float* fr = fused + (size_t)row * OD;
  const int c0 = t * 8;
  float v[8];
  float s = 0.f, ss = 0.f;
#pragma unroll
  for (int j = 0; j < 2; ++j) {
    float4 x  = *(const float4*)(fr  + c0 + j * 4);
    float4 bq = *(const float4*)(beq + c0 + j * 4);
    float4 bb = *(const float4*)(bfv + c0 + j * 4);
    v[j * 4 + 0] = x.x + bq.x + bb.x;
    v[j * 4 + 1] = x.y + bq.y + bb.y;
    v[j * 4 + 2] = x.z + bq.z + bb.z;
    v[j * 4 + 3] = x.w + bq.w + bb.w;
#pragma unroll
    for (int e = 0; e < 4; ++e) { float w = v[j * 4 + e]; s += w; ss += w * w; }
  }
  s = wave_sum(s); ss = wave_sum(ss);
  __shared__ float rs[4], rss[4];
  if ((t & 63) == 0) { rs[t >> 6] = s; rss[t >> 6] = ss; }
  __syncthreads();
  const float S  = rs[0] + rs[1] + rs[2] + rs[3];
  const float SS = rss[0] + rss[1] + rss[2] + rss[3];
  const float mu   = S * (1.f / OD);
  const float var  = SS * (1.f / OD) - mu * mu;
  const float rstd = rsqrtf(var + 1e-5f);
#pragma unroll
  for (int j = 0; j < 2; ++j) {
    float4 g  = *(const float4*)(gamma + c0 + j * 4);
    float4 be = *(const float4*)(beta  + c0 + j * 4);
    float4 o;
    float xn;
    xn  = (v[j * 4 + 0] - mu) * rstd * g.x + be.x; o.x = 0.5f * xn * (1.f + erff(xn * 0.70710678118f));
    xn  = (v[j * 4 + 1] - mu) * rstd * g.y + be.y; o.y = 0.5f * xn * (1.f + erff(xn * 0.70710678118f));
    xn  = (v[j * 4 + 2] - mu) * rstd * g.z + be.z; o.z = 0.5f * xn * (1.f + erff(xn * 0.70710678118f));
    xn  = (v[j * 4 + 3] - mu) * rstd * g.w + be.w; o.w = 0.5f * xn * (1.f + erff(xn * 0.70710678118f));
    *(float4*)(out + (size_t)row * OD + c0 + j * 4) = o;
  }
}

extern "C" void kernel_launch(void* const* d_in, const int* in_sizes, int n_in,
                              void* d_out, int out_size, void* d_ws, size_t ws_size,
                              hipStream_t stream) {
  const float* x     = (const float*)d_in[0];
  const float* W16   = (const float*)d_in[1];
  const float* b16   = (const float*)d_in[2];
  const float* Wf    = (const float*)d_in[3];
  const float* bfv   = (const float*)d_in[4];
  const float* gamma = (const float*)d_in[5];
  const float* beta  = (const float*)d_in[6];
  float* out = (float*)d_out;

  char* ws = (char*)d_ws;
  bf16_t* W16T  = (bf16_t*)(ws);                 // [2048][32768] bf16, 128 MiB
  bf16_t* Wf16  = (bf16_t*)(ws + 134217728);     // [2048][32768] bf16, 128 MiB
  bf16_t* X16   = (bf16_t*)(ws + 268435456);     // [8192][2048] bf16, 32 MiB
  bf16_t* Weq   = (bf16_t*)(ws + 301989888);     // [2048][2048] bf16, 8 MiB
  float*  beq   = (float*)(ws + 310378496);      // [2048] f32
  float*  slabs = (float*)(ws + 310386688);      // 4 x 16 MiB f32; reused as fused
  float*  fused = slabs;

  hipMemsetAsync(beq, 0, OD * sizeof(float), stream);

  conv_wf_beq<<<dim3(16, 2048), 256, 0, stream>>>(Wf, b16, Wf16, beq);
  transpose_w16<<<dim3(KC / 64, ID / 64), 256, 0, stream>>>(W16, W16T);
  conv_x<<<(BSROWS * ID) / (256 * 8), 256, 0, stream>>>(x, X16);

  // GEMM1: Weq = Wf16 [2048][32768] * W16T^T, K-split 4 -> slabs (grid 256)
  gemm256<<<256, 512, 0, stream>>>(Wf16, W16T, slabs, OD, ID, KC, KC, KC / 4, 8, 64);
  reduce_weq<<<(OD * ID) / (256 * 4), 256, 0, stream>>>(slabs, Weq);

  // GEMM2: fused = X16 [8192][2048] * Weq^T [2048][2048] (grid 32x8 = 256)
  gemm256<<<256, 512, 0, stream>>>(X16, Weq, fused, BSROWS, OD, ID, ID, ID, 8, 256);

  ln_gelu<<<BSROWS, 256, 0, stream>>>(fused, beq, bfv, gamma, beta, out);
}

// Round 8
// 537.012 us; speedup vs baseline: 1.8474x; 1.8474x over previous
//
#include <hip/hip_runtime.h>
#include <hip/hip_bf16.h>
#include <math.h>

// QuantumNeuralLayer collapsed: fused = x @ Weq^T + beq, Weq = Wf @ W16r.
// R8 GEMM: m201-schedule port with provable counted gates.
// 256x256 tile, 8 waves (2M x 4N), K-tile = 64. LDS 128 KiB:
//   A: 2 buffers x 32 KiB (dbuf by tile parity)
//   B: ring-4 of 16 KiB col-half-tiles (slot = (2*tile + colhalf) & 3)
// 4 phases per K-tile t: phase p = {ds_read A-quad p (+ B(t+1) k-half on p3/p4);
//   stage 2 GLL (A(t+1) halves on p1/p2, B(t+2) halves on p3/p4); barrier;
//   lgkmcnt(0); 16 MFMA}. Gates: vmcnt(4)+barrier at end of p2 and p4 only.
// B regs double-buffered across tiles (filled from LDS during p3/p4 of t-1).
// 128B LDS rows with slot^=(row&7) swizzle (R6-verified conflict-free,
// both-sides: linear GLL dest + inverse-permuted global source).

typedef __bf16 bf16_t;
typedef __bf16 bf16x8 __attribute__((ext_vector_type(8)));
typedef __bf16 bf16x4 __attribute__((ext_vector_type(4)));
typedef float  f32x4  __attribute__((ext_vector_type(4)));

#define KC 32768
#define OD 2048
#define ID 2048
#define BSROWS 8192

#define GLL16(g, l) __builtin_amdgcn_global_load_lds( \
    (const __attribute__((address_space(1))) void*)(g), \
    (__attribute__((address_space(3))) void*)(l), 16, 0, 0)

__device__ __forceinline__ float wave_sum(float v) {
#pragma unroll
  for (int o = 32; o > 0; o >>= 1) v += __shfl_down(v, o, 64);
  return v;
}

__global__ __launch_bounds__(512, 1) void gemm256(
    const bf16_t* __restrict__ A, const bf16_t* __restrict__ B,
    float* __restrict__ C, int M, int N, int lda, int ldb,
    int Ks, int nbn, int mn)
{
  __shared__ char lds[131072];   // A: [0,65536) two 32K bufs; B: [65536,131072) four 16K slots
  const int tid  = threadIdx.x;
  const int lane = tid & 63;
  const int wave = tid >> 6;

  // T1: bijective XCD swizzle (gridDim.x % 8 == 0)
  const int nwg = gridDim.x;
  const int per = nwg >> 3;
  const int swz = (blockIdx.x & 7) * per + (blockIdx.x >> 3);
  const int z   = swz / mn;
  const int rem = swz - z * mn;
  const int bm  = (rem / nbn) * 256;
  const int bn  = (rem % nbn) * 256;
  const int k0  = z * Ks;
  float* Cz = C + (size_t)z * ((size_t)M * (size_t)N);

  const int wr = wave >> 2, wc = wave & 3;
  const int frow  = lane & 15;
  const int bhalf = wc >> 1;                       // which B col-half this wave consumes

  // read-side swizzled 16B-slot byte offsets for the two K32 halves (R6-verified)
  const int rdsl0 = (((lane >> 4))     ^ (lane & 7)) * 16;
  const int rdsl1 = (((lane >> 4) + 4) ^ (lane & 7)) * 16;

  const int abase = wr * 16384 + frow * 128;       // within A buffer
  const int bloc  = ((wc & 1) * 64 + frow) * 128;  // within B slot

  // stage-side: thread covers row tid>>3 (+64 per sweep); slot inverse-swizzled
  const int srow8 = tid >> 3;
  const int sw8   = (tid & 7) ^ (srow8 & 7);
  const bf16_t* gA0 = A + (size_t)(bm + srow8) * lda + k0 + sw8 * 8;
  const bf16_t* gB0 = B + (size_t)(bn + srow8) * ldb + k0 + sw8 * 8;
  const int ldw = wave * 1024;                     // + lane*16 implicit in GLL

  f32x4 acc[8][4] = {};
  bf16x8 aqE[2][2], aqO[2][2], bA[4][2], bB[4][2];
  const int NT = Ks >> 6;                          // K64 tiles; even, >= 4

#define STAGE_A_HALF(t, hf) do {                                          \
    _Pragma("unroll") for (int s_ = 0; s_ < 2; ++s_)                      \
      GLL16(gA0 + (size_t)((hf) * 128 + s_ * 64) * lda + (size_t)(t) * 64,\
            lds + (((t) & 1) << 15) + (hf) * 16384 + s_ * 8192 + ldw);    \
  } while (0)

#define STAGE_B_HALF(t, hh) do {                                          \
    _Pragma("unroll") for (int s_ = 0; s_ < 2; ++s_)                      \
      GLL16(gB0 + (size_t)((hh) * 128 + s_ * 64) * ldb + (size_t)(t) * 64,\
            lds + 65536 + ((((t) * 2 + (hh)) & 3) << 14) + s_ * 8192 + ldw); \
  } while (0)

#define READ_AQ(t, q, aq) do {                                            \
    const char* p_ = lds + (((t) & 1) << 15) + abase + (q) * 4096;        \
    aq[0][0] = *reinterpret_cast<const bf16x8*>(p_ + rdsl0);              \
    aq[0][1] = *reinterpret_cast<const bf16x8*>(p_ + rdsl1);              \
    aq[1][0] = *reinterpret_cast<const bf16x8*>(p_ + 2048 + rdsl0);       \
    aq[1][1] = *reinterpret_cast<const bf16x8*>(p_ + 2048 + rdsl1);       \
  } while (0)

#define READ_BH(t, kh, bg) do {                                           \
    const char* p_ = lds + 65536 + ((((t) * 2 + bhalf) & 3) << 14) + bloc;\
    _Pragma("unroll") for (int n_ = 0; n_ < 4; ++n_)                      \
      bg[n_][kh] = *reinterpret_cast<const bf16x8*>(                      \
          p_ + n_ * 2048 + ((kh) ? rdsl1 : rdsl0));                       \
  } while (0)

#define SYNCPH() do {                                                     \
    __builtin_amdgcn_s_barrier();                                         \
    asm volatile("s_waitcnt lgkmcnt(0)" ::: "memory");                    \
    __builtin_amdgcn_sched_barrier(0);                                    \
  } while (0)

#define MFMA_Q(q, aq, bg) do {                                            \
    __builtin_amdgcn_s_setprio(1);                                        \
    _Pragma("unroll") for (int mh_ = 0; mh_ < 2; ++mh_)                   \
      _Pragma("unroll") for (int n_ = 0; n_ < 4; ++n_) {                  \
        acc[2*(q)+mh_][n_] = __builtin_amdgcn_mfma_f32_16x16x32_bf16(     \
            aq[mh_][0], bg[n_][0], acc[2*(q)+mh_][n_], 0, 0, 0);          \
        acc[2*(q)+mh_][n_] = __builtin_amdgcn_mfma_f32_16x16x32_bf16(     \
            aq[mh_][1], bg[n_][1], acc[2*(q)+mh_][n_], 0, 0, 0);          \
      }                                                                   \
    __builtin_amdgcn_s_setprio(0);                                        \
  } while (0)

  // TILE(t): 4 phases. BC = B regs for tile t (filled during t-1);
  // BN = shadow regs filled with B(t+1) during p3/p4.
#define TILE(t, BC, BN) do {                                              \
    /* p1 */                                                              \
    if ((t) + 1 < NT) STAGE_A_HALF((t) + 1, 0);                           \
    READ_AQ((t), 0, aqE);                                                 \
    SYNCPH(); MFMA_Q(0, aqE, BC);                                         \
    /* p2 */                                                              \
    if ((t) + 1 < NT) STAGE_A_HALF((t) + 1, 1);                           \
    READ_AQ((t), 1, aqO);                                                 \
    SYNCPH(); MFMA_Q(1, aqO, BC);                                         \
    if ((t) + 1 < NT) {  /* gate: B(t+1) landed (counted) */              \
      asm volatile("s_waitcnt vmcnt(4)" ::: "memory");                    \
      __builtin_amdgcn_s_barrier();                                       \
    }                                                                     \
    /* p3 */                                                              \
    if ((t) + 2 < NT) STAGE_B_HALF((t) + 2, 0);                           \
    READ_AQ((t), 2, aqE);                                                 \
    if ((t) + 1 < NT) READ_BH((t) + 1, 0, BN);                            \
    SYNCPH(); MFMA_Q(2, aqE, BC);                                         \
    /* p4 */                                                              \
    if ((t) + 2 < NT) STAGE_B_HALF((t) + 2, 1);                           \
    READ_AQ((t), 3, aqO);                                                 \
    if ((t) + 1 < NT) READ_BH((t) + 1, 1, BN);                            \
    SYNCPH(); MFMA_Q(3, aqO, BC);                                         \
    if ((t) + 2 < NT) {  /* gate: A(t+1) landed (counted) */              \
      asm volatile("s_waitcnt vmcnt(4)" ::: "memory");                    \
      __builtin_amdgcn_s_barrier();                                       \
    } else if ((t) + 1 < NT) {                                            \
      asm volatile("s_waitcnt vmcnt(0)" ::: "memory");  /* tail drain */  \
      __builtin_amdgcn_s_barrier();                                       \
    }                                                                     \
  } while (0)

  // prologue: stage A(0), B(0), B(1); gate A(0)+B(0); fill bA = B(0)
  STAGE_A_HALF(0, 0); STAGE_A_HALF(0, 1);
  STAGE_B_HALF(0, 0); STAGE_B_HALF(0, 1);
  STAGE_B_HALF(1, 0); STAGE_B_HALF(1, 1);
  asm volatile("s_waitcnt vmcnt(4)" ::: "memory");   // drain A(0)+B(0); B(1) in flight
  __builtin_amdgcn_s_barrier();
  READ_BH(0, 0, bA);
  READ_BH(0, 1, bA);
  asm volatile("s_waitcnt lgkmcnt(0)" ::: "memory");
  __builtin_amdgcn_sched_barrier(0);
  __builtin_amdgcn_s_barrier();                      // B(0) slot reads drained collectively

#pragma unroll 1
  for (int t = 0; t < NT; t += 2) {
    TILE(t,     bA, bB);
    TILE(t + 1, bB, bA);
  }
#undef TILE
#undef MFMA_Q
#undef SYNCPH
#undef READ_BH
#undef READ_AQ
#undef STAGE_B_HALF
#undef STAGE_A_HALF

  // C/D layout (m89-verified): col = lane&15, row = (lane>>4)*4 + j
  const int wrbase = wr * 128, wcbase = wc * 64;
  const int cr = (lane >> 4) * 4, cc = lane & 15;
#pragma unroll
  for (int m = 0; m < 8; ++m)
#pragma unroll
    for (int n = 0; n < 4; ++n) {
      size_t base = (size_t)(bm + wrbase + m * 16 + cr) * N + (bn + wcbase + n * 16 + cc);
#pragma unroll
      for (int j = 0; j < 4; ++j)
        Cz[base + (size_t)j * N] = acc[m][n][j];
    }
}

// ---------------- Wf f32 -> bf16, and beq partial = sum_c b16[c]*Wf[o,c] ----------
__global__ void conv_wf_beq(const float* __restrict__ Wf, const float* __restrict__ b16,
                            bf16_t* __restrict__ Wf16, float* __restrict__ beq)
{
  const int o  = blockIdx.y;
  const int cb = blockIdx.x * 2048;
  const int t  = threadIdx.x;
  const size_t gbase = (size_t)o * KC + cb + t * 8;
  const float4 v0 = *(const float4*)(Wf + gbase);
  const float4 v1 = *(const float4*)(Wf + gbase + 4);
  const float4 b0 = *(const float4*)(b16 + cb + t * 8);
  const float4 b1 = *(const float4*)(b16 + cb + t * 8 + 4);
  bf16x8 r;
  r[0] = (bf16_t)v0.x; r[1] = (bf16_t)v0.y; r[2] = (bf16_t)v0.z; r[3] = (bf16_t)v0.w;
  r[4] = (bf16_t)v1.x; r[5] = (bf16_t)v1.y; r[6] = (bf16_t)v1.z; r[7] = (bf16_t)v1.w;
  *reinterpret_cast<bf16x8*>(Wf16 + gbase) = r;
  float s = v0.x * b0.x + v0.y * b0.y + v0.z * b0.z + v0.w * b0.w
          + v1.x * b1.x + v1.y * b1.y + v1.z * b1.z + v1.w * b1.w;
  s = wave_sum(s);
  __shared__ float red[4];
  if ((t & 63) == 0) red[t >> 6] = s;
  __syncthreads();
  if (t == 0) atomicAdd(beq + o, red[0] + red[1] + red[2] + red[3]);
}

// ---------------- W16 [c][i] f32 -> W16T [i][c] bf16 (vectorized writes) ----------
__global__ void transpose_w16(const float* __restrict__ W, bf16_t* __restrict__ T)
{
  __shared__ bf16_t tile[64][65];
  const int cb = blockIdx.x * 64;
  const int ib = blockIdx.y * 64;
  const int tx = threadIdx.x & 63;
  const int ty = threadIdx.x >> 6;
#pragma unroll
  for (int r = ty; r < 64; r += 4)
    tile[r][tx] = (bf16_t)W[(size_t)(cb + r) * ID + ib + tx];
  __syncthreads();
  const int orow = threadIdx.x >> 3;
  const int oc8  = (threadIdx.x & 7) * 8;
#pragma unroll
  for (int rr = 0; rr < 2; ++rr) {
    const int r = orow + rr * 32;
    bf16x8 v;
#pragma unroll
    for (int j = 0; j < 8; ++j) v[j] = tile[oc8 + j][r];
    *reinterpret_cast<bf16x8*>(T + (size_t)(ib + r) * KC + cb + oc8) = v;
  }
}

// ---------------- x f32 -> bf16 ---------------------------------------------------
__global__ void conv_x(const float* __restrict__ X, bf16_t* __restrict__ X16)
{
  const size_t i = ((size_t)blockIdx.x * 256 + threadIdx.x) * 8;
  const float4 v0 = *(const float4*)(X + i);
  const float4 v1 = *(const float4*)(X + i + 4);
  bf16x8 r;
  r[0] = (bf16_t)v0.x; r[1] = (bf16_t)v0.y; r[2] = (bf16_t)v0.z; r[3] = (bf16_t)v0.w;
  r[4] = (bf16_t)v1.x; r[5] = (bf16_t)v1.y; r[6] = (bf16_t)v1.z; r[7] = (bf16_t)v1.w;
  *reinterpret_cast<bf16x8*>(X16 + i) = r;
}

// ---------------- reduce 4 K-split slabs -> Weq bf16 ------------------------------
__global__ void reduce_weq(const float* __restrict__ slabs, bf16_t* __restrict__ Weq)
{
  const size_t MN = (size_t)OD * ID;
  const size_t i = ((size_t)blockIdx.x * 256 + threadIdx.x) * 4;
  float4 a = *(const float4*)(slabs + i);
  float4 b = *(const float4*)(slabs + MN + i);
  float4 c = *(const float4*)(slabs + 2 * MN + i);
  float4 d = *(const float4*)(slabs + 3 * MN + i);
  bf16x4 r;
  r[0] = (bf16_t)(a.x + b.x + c.x + d.x);
  r[1] = (bf16_t)(a.y + b.y + c.y + d.y);
  r[2] = (bf16_t)(a.z + b.z + c.z + d.z);
  r[3] = (bf16_t)(a.w + b.w + c.w + d.w);
  *reinterpret_cast<bf16x4*>(Weq + i) = r;
}

// ---------------- bias + LayerNorm + exact GELU -----------------------------------
__global__ __launch_bounds__(256) void ln_gelu(
    const float* __restrict__ fused, const float* __restrict__ beq,
    const float* __restrict__ bfv, const float* __restrict__ gamma,
    const float* __restrict__ beta, float* __restrict__ out)
{
  const int row = blockIdx.x;
  const int t = threadIdx.x;
  const float* fr = fused + (size_t)row * OD;
  const int c0 = t * 8;
  float v[8];
  float s = 0.f, ss = 0.f;
#pragma unroll
  for (int j = 0; j < 2; ++j) {
    float4 x  = *(const float4*)(fr  + c0 + j * 4);
    float4 bq = *(const float4*)(beq + c0 + j * 4);
    float4 bb = *(const float4*)(bfv + c0 + j * 4);
    v[j * 4 + 0] = x.x + bq.x + bb.x;
    v[j * 4 + 1] = x.y + bq.y + bb.y;
    v[j * 4 + 2] = x.z + bq.z + bb.z;
    v[j * 4 + 3] = x.w + bq.w + bb.w;
#pragma unroll
    for (int e = 0; e < 4; ++e) { float w = v[j * 4 + e]; s += w; ss += w * w; }
  }
  s = wave_sum(s); ss = wave_sum(ss);
  __shared__ float rs[4], rss[4];
  if ((t & 63) == 0) { rs[t >> 6] = s; rss[t >> 6] = ss; }
  __syncthreads();
  const float S  = rs[0] + rs[1] + rs[2] + rs[3];
  const float SS = rss[0] + rss[1] + rss[2] + rss[3];
  const float mu   = S * (1.f / OD);
  const float var  = SS * (1.f / OD) - mu * mu;
  const float rstd = rsqrtf(var + 1e-5f);
#pragma unroll
  for (int j = 0; j < 2; ++j) {
    float4 g  = *(const float4*)(gamma + c0 + j * 4);
    float4 be = *(const float4*)(beta  + c0 + j * 4);
    float4 o;
    float xn;
    xn  = (v[j * 4 + 0] - mu) * rstd * g.x + be.x; o.x = 0.5f * xn * (1.f + erff(xn * 0.70710678118f));
    xn  = (v[j * 4 + 1] - mu) * rstd * g.y + be.y; o.y = 0.5f * xn * (1.f + erff(xn * 0.70710678118f));
    xn  = (v[j * 4 + 2] - mu) * rstd * g.z + be.z; o.z = 0.5f * xn * (1.f + erff(xn * 0.70710678118f));
    xn  = (v[j * 4 + 3] - mu) * rstd * g.w + be.w; o.w = 0.5f * xn * (1.f + erff(xn * 0.70710678118f));
    *(float4*)(out + (size_t)row * OD + c0 + j * 4) = o;
  }
}

extern "C" void kernel_launch(void* const* d_in, const int* in_sizes, int n_in,
                              void* d_out, int out_size, void* d_ws, size_t ws_size,
                              hipStream_t stream) {
  const float* x     = (const float*)d_in[0];
  const float* W16   = (const float*)d_in[1];
  const float* b16   = (const float*)d_in[2];
  const float* Wf    = (const float*)d_in[3];
  const float* bfv   = (const float*)d_in[4];
  const float* gamma = (const float*)d_in[5];
  const float* beta  = (const float*)d_in[6];
  float* out = (float*)d_out;

  char* ws = (char*)d_ws;
  bf16_t* W16T  = (bf16_t*)(ws);                 // [2048][32768] bf16, 128 MiB
  bf16_t* Wf16  = (bf16_t*)(ws + 134217728);     // [2048][32768] bf16, 128 MiB
  bf16_t* X16   = (bf16_t*)(ws + 268435456);     // [8192][2048] bf16, 32 MiB
  bf16_t* Weq   = (bf16_t*)(ws + 301989888);     // [2048][2048] bf16, 8 MiB
  float*  beq   = (float*)(ws + 310378496);      // [2048] f32
  float*  slabs = (float*)(ws + 310386688);      // 4 x 16 MiB f32; reused as fused
  float*  fused = slabs;

  hipMemsetAsync(beq, 0, OD * sizeof(float), stream);

  conv_wf_beq<<<dim3(16, 2048), 256, 0, stream>>>(Wf, b16, Wf16, beq);
  transpose_w16<<<dim3(KC / 64, ID / 64), 256, 0, stream>>>(W16, W16T);
  conv_x<<<(BSROWS * ID) / (256 * 8), 256, 0, stream>>>(x, X16);

  // GEMM1: Weq = Wf16 [2048][32768] * W16T^T, K-split 4 -> slabs (grid 256)
  gemm256<<<256, 512, 0, stream>>>(Wf16, W16T, slabs, OD, ID, KC, KC, KC / 4, 8, 64);
  reduce_weq<<<(OD * ID) / (256 * 4), 256, 0, stream>>>(slabs, Weq);

  // GEMM2: fused = X16 [8192][2048] * Weq^T [2048][2048] (grid 32x8 = 256)
  gemm256<<<256, 512, 0, stream>>>(X16, Weq, fused, BSROWS, OD, ID, ID, ID, 8, 256);

  ln_gelu<<<BSROWS, 256, 0, stream>>>(fused, beq, bfv, gamma, beta, out);
}